// Round 1
// baseline (6483.616 us; speedup 1.0000x reference)
//
#include <hip/hip_runtime.h>
#include <math.h>

#define BATCH 16
#define HID   128
#define NX    128
#define NF    4
#define NT    64
#define MODES 96

// ---------------------------------------------------------------------------
// Tables: C[m][x] = cos(2*pi*k_m*x/128), S[m][x] = sin(...), k_m = (80+m)%128
// ---------------------------------------------------------------------------
__global__ void k_tables(float* __restrict__ C, float* __restrict__ S) {
    int m = blockIdx.x;
    int x = threadIdx.x;
    if (x < NX) {
        int k = (80 + m) % NX;
        float ang = (float)((k * x) & (NX - 1)) * (2.0f * (float)M_PI / (float)NX);
        C[m * NX + x] = cosf(ang);
        S[m * NX + x] = sinf(ang);
    }
}

// ---------------------------------------------------------------------------
// dxi[t][b][x][n] = xi[b,n,x,t+1] - xi[b,n,x,t]   (xi layout: (b,n,x,t))
// ---------------------------------------------------------------------------
__global__ void k_dxi(const float* __restrict__ xi, float* __restrict__ dxi) {
    int idx = blockIdx.x * blockDim.x + threadIdx.x;
    const int total = (NT - 1) * BATCH * NX * NF;
    if (idx < total) {
        int n = idx & (NF - 1);
        int x = (idx >> 2) & (NX - 1);
        int b = (idx >> 9) & (BATCH - 1);
        int t = idx >> 13;
        const float* base = xi + (((size_t)b * NF + n) * NX + x) * NT;
        dxi[idx] = base[t + 1] - base[t];
    }
}

// ---------------------------------------------------------------------------
// v0[b][c][m][h]: band-limited shifted FFT of z0 along x.
//   re = sum_x z0[b,h,x] * C[m,x];  im = -sum_x z0[b,h,x] * S[m,x]
// grid (96, 16), block 256 (tid -> h = tid&127, c = tid>>7)
// ---------------------------------------------------------------------------
__global__ __launch_bounds__(256) void k_v0(const float* __restrict__ z0,
                                            const float* __restrict__ C,
                                            const float* __restrict__ S,
                                            float* __restrict__ v) {
    int m = blockIdx.x, b = blockIdx.y;
    int h = threadIdx.x & 127;
    int c = threadIdx.x >> 7;
    const float* zr = z0 + ((size_t)b * HID + h) * NX;
    const float* T  = (c == 0) ? (C + m * NX) : (S + m * NX);
    float acc = 0.f;
    for (int x = 0; x < NX; ++x) acc += zr[x] * T[x];
    if (c) acc = -acc;
    v[(((size_t)b * 2 + c) * MODES + m) * HID + h] = acc;
}

// ---------------------------------------------------------------------------
// K1: per step i.
//  Phase A: z[b,h,x] = (1/128) * sum_m (vre[b,m,h]*C[m,x] - vim[b,m,h]*S[m,x])
//           -> LDS, and -> out[b,h,x,step]
//  Phase B: H[b,o,x] = tanh(sum_h WF[o,h] z[h,x])
//                    + sum_n tanh(sum_h WG[o,n,h] z[h,x]) * dxi[step,b,x,n]
// grid (16 x-tiles of 8, 16 b), block 256.
// ---------------------------------------------------------------------------
__global__ __launch_bounds__(256) void k_step1(
    const float* __restrict__ v, const float* __restrict__ C,
    const float* __restrict__ S, const float* __restrict__ WF,
    const float* __restrict__ WG, const float* __restrict__ dxi,
    float* __restrict__ H, float* __restrict__ out, int step, int writeH)
{
    __shared__ float zs[HID][8];
    int xt  = blockIdx.x;   // 0..15
    int b   = blockIdx.y;   // 0..15
    int tid = threadIdx.x;

    // ---- Phase A: z ----
    {
        int x  = tid & 7;
        int hh = tid >> 3;            // 0..31
        int xg = xt * 8 + x;
        float acc0 = 0.f, acc1 = 0.f, acc2 = 0.f, acc3 = 0.f;
        for (int m = 0; m < MODES; ++m) {
            float c = C[m * NX + xg];
            float s = S[m * NX + xg];
            const float* vr = v + (((size_t)b * 2 + 0) * MODES + m) * HID;
            const float* vi = v + (((size_t)b * 2 + 1) * MODES + m) * HID;
            acc0 += vr[hh      ] * c - vi[hh      ] * s;
            acc1 += vr[hh + 32 ] * c - vi[hh + 32 ] * s;
            acc2 += vr[hh + 64 ] * c - vi[hh + 64 ] * s;
            acc3 += vr[hh + 96 ] * c - vi[hh + 96 ] * s;
        }
        const float inv = 1.0f / (float)NX;
        float z0v = acc0 * inv, z1v = acc1 * inv, z2v = acc2 * inv, z3v = acc3 * inv;
        zs[hh      ][x] = z0v;
        zs[hh + 32 ][x] = z1v;
        zs[hh + 64 ][x] = z2v;
        zs[hh + 96 ][x] = z3v;
        size_t ob = (((size_t)b * HID) * NX + xg) * NT + step;
        out[ob + (size_t)(hh      ) * NX * NT] = z0v;
        out[ob + (size_t)(hh + 32 ) * NX * NT] = z1v;
        out[ob + (size_t)(hh + 64 ) * NX * NT] = z2v;
        out[ob + (size_t)(hh + 96 ) * NX * NT] = z3v;
    }
    __syncthreads();
    if (!writeH) return;

    // ---- Phase B: H ----
    {
        int o  = tid & 127;
        int xp = tid >> 7;            // 0 or 1
        int x0 = xp * 4;
        float accF[4]    = {0.f, 0.f, 0.f, 0.f};
        float accG[NF][4] = {};
        const float* wf = WF + (size_t)o * HID;
        const float* wg = WG + (size_t)o * NF * HID;
        for (int h = 0; h < HID; ++h) {
            float zv0 = zs[h][x0 + 0];
            float zv1 = zs[h][x0 + 1];
            float zv2 = zs[h][x0 + 2];
            float zv3 = zs[h][x0 + 3];
            float f = wf[h];
            accF[0] += f * zv0; accF[1] += f * zv1;
            accF[2] += f * zv2; accF[3] += f * zv3;
            #pragma unroll
            for (int n = 0; n < NF; ++n) {
                float g = wg[(size_t)n * HID + h];
                accG[n][0] += g * zv0; accG[n][1] += g * zv1;
                accG[n][2] += g * zv2; accG[n][3] += g * zv3;
            }
        }
        int xg0 = xt * 8 + x0;
        const float* dx = dxi + ((((size_t)step * BATCH + b) * NX) + xg0) * NF;
        #pragma unroll
        for (int k = 0; k < 4; ++k) {
            float hv = tanhf(accF[k]);
            #pragma unroll
            for (int n = 0; n < NF; ++n)
                hv += tanhf(accG[n][k]) * dx[k * NF + n];
            H[((size_t)b * HID + o) * NX + xg0 + k] = hv;
        }
    }
}

// ---------------------------------------------------------------------------
// K2: per step. For each mode m, o-quarter:
//  fft_re[b,m,o] =  sum_x H[b,o,x]*C[m,x];  fft_im = -sum_x H[b,o,x]*S[m,x]
//  Av_re = sum_h A0[m,o,h]*vre[b,m,h] - A1[m,o,h]*vim[b,m,h]
//  Av_im = sum_h A1[m,o,h]*vre[b,m,h] - A0[m,o,h]*vim[b,m,h]   (faithful sign)
//  vout = vin + Av + fft
// grid (4 o-quarters, 96 m), block 256.
// ---------------------------------------------------------------------------
__global__ __launch_bounds__(256) void k_step2(
    const float* __restrict__ vin, const float* __restrict__ A,
    const float* __restrict__ C, const float* __restrict__ S,
    const float* __restrict__ H, float* __restrict__ vout)
{
    int oq = blockIdx.x;   // 0..3
    int m  = blockIdx.y;   // 0..95
    int tid = threadIdx.x;
    __shared__ float vres[BATCH][HID];
    __shared__ float vims[BATCH][HID];
    __shared__ float Cs[NX], Ss[NX];
    if (tid < NX) { Cs[tid] = C[m * NX + tid]; Ss[tid] = S[m * NX + tid]; }
    for (int f = tid; f < BATCH * HID; f += 256) {
        int b = f >> 7, h = f & 127;
        vres[b][h] = vin[(((size_t)b * 2 + 0) * MODES + m) * HID + h];
        vims[b][h] = vin[(((size_t)b * 2 + 1) * MODES + m) * HID + h];
    }
    __syncthreads();
    const float* A0 = A + ((size_t)0 * MODES + m) * HID * HID;
    const float* A1 = A + ((size_t)1 * MODES + m) * HID * HID;
    #pragma unroll
    for (int pass = 0; pass < 2; ++pass) {
        int ol = tid & 31;
        int b  = (tid >> 5) + pass * 8;
        int o  = oq * 32 + ol;
        const float* Hrow = H + ((size_t)b * HID + o) * NX;
        float fre = 0.f, fim = 0.f;
        for (int x = 0; x < NX; ++x) {
            float hv = Hrow[x];
            fre += hv * Cs[x];
            fim -= hv * Ss[x];
        }
        const float* a0 = A0 + (size_t)o * HID;
        const float* a1 = A1 + (size_t)o * HID;
        float are = 0.f, aim = 0.f;
        for (int h = 0; h < HID; ++h) {
            float r = vres[b][h], i2 = vims[b][h];
            are += a0[h] * r - a1[h] * i2;
            aim += a1[h] * r - a0[h] * i2;
        }
        vout[(((size_t)b * 2 + 0) * MODES + m) * HID + o] = vres[b][o] + are + fre;
        vout[(((size_t)b * 2 + 1) * MODES + m) * HID + o] = vims[b][o] + aim + fim;
    }
}

// ---------------------------------------------------------------------------
extern "C" void kernel_launch(void* const* d_in, const int* in_sizes, int n_in,
                              void* d_out, int out_size, void* d_ws, size_t ws_size,
                              hipStream_t stream) {
    const float* z0 = (const float*)d_in[0];
    const float* xi = (const float*)d_in[1];
    const float* A  = (const float*)d_in[2];
    const float* WF = (const float*)d_in[3];
    const float* WG = (const float*)d_in[4];
    float* out = (float*)d_out;

    float* ws = (float*)d_ws;
    float* C    = ws;                          // 96*128
    float* S    = C + MODES * NX;              // 96*128
    float* v0b  = S + MODES * NX;              // 16*2*96*128
    float* v1b  = v0b + BATCH * 2 * MODES * HID;
    float* Hb   = v1b + BATCH * 2 * MODES * HID; // 16*128*128
    float* dxib = Hb + BATCH * HID * NX;       // 63*16*128*4

    k_tables<<<MODES, 128, 0, stream>>>(C, S);
    {
        int total = (NT - 1) * BATCH * NX * NF;
        k_dxi<<<(total + 255) / 256, 256, 0, stream>>>(xi, dxib);
    }
    k_v0<<<dim3(MODES, BATCH), 256, 0, stream>>>(z0, C, S, v0b);

    float* vcur = v0b;
    float* vnxt = v1b;
    for (int i = 0; i < NT - 1; ++i) {
        k_step1<<<dim3(16, BATCH), 256, 0, stream>>>(vcur, C, S, WF, WG, dxib,
                                                     Hb, out, i, 1);
        k_step2<<<dim3(4, MODES), 256, 0, stream>>>(vcur, A, C, S, Hb, vnxt);
        float* t = vcur; vcur = vnxt; vnxt = t;
    }
    // final trajectory column t = 63 (z from v_63 only)
    k_step1<<<dim3(16, BATCH), 256, 0, stream>>>(vcur, C, S, WF, WG, dxib,
                                                 Hb, out, NT - 1, 0);
}

// Round 2
// 5220.274 us; speedup vs baseline: 1.2420x; 1.2420x over previous
//
#include <hip/hip_runtime.h>
#include <math.h>

#define BATCH 16
#define HID   128
#define NX    128
#define NF    4
#define NT    64
#define MODES 96
#define XT    4           // x-tile per k_step1 workgroup
#define NXT   (NX / XT)   // 32 tiles -> grid (32,16) = 512 WGs

// ---------------------------------------------------------------------------
// Tables: C[m][x] = cos(2*pi*k_m*x/128), S[m][x] = sin(...), k_m = (80+m)%128
// ---------------------------------------------------------------------------
__global__ void k_tables(float* __restrict__ C, float* __restrict__ S) {
    int m = blockIdx.x;
    int x = threadIdx.x;
    if (x < NX) {
        int k = (80 + m) % NX;
        float ang = (float)((k * x) & (NX - 1)) * (2.0f * (float)M_PI / (float)NX);
        C[m * NX + x] = cosf(ang);
        S[m * NX + x] = sinf(ang);
    }
}

// ---------------------------------------------------------------------------
// dxi[t][b][x][n] = xi[b,n,x,t+1] - xi[b,n,x,t]   (xi layout: (b,n,x,t))
// ---------------------------------------------------------------------------
__global__ void k_dxi(const float* __restrict__ xi, float* __restrict__ dxi) {
    int idx = blockIdx.x * blockDim.x + threadIdx.x;
    const int total = (NT - 1) * BATCH * NX * NF;
    if (idx < total) {
        int n = idx & (NF - 1);
        int x = (idx >> 2) & (NX - 1);
        int b = (idx >> 9) & (BATCH - 1);
        int t = idx >> 13;
        const float* base = xi + (((size_t)b * NF + n) * NX + x) * NT;
        dxi[idx] = base[t + 1] - base[t];
    }
}

// ---------------------------------------------------------------------------
// Tiled transpose: src (R x C, row-major) -> dst (C x R). blockIdx.z = matrix.
// block (32,8), grid (C/32, R/32, nmat).
// ---------------------------------------------------------------------------
__global__ void k_transpose(const float* __restrict__ src, float* __restrict__ dst,
                            int R, int C) {
    __shared__ float tile[32][33];
    int mat = blockIdx.z;
    const float* s = src + (size_t)mat * R * C;
    float* d = dst + (size_t)mat * R * C;
    int c0 = blockIdx.x * 32, r0 = blockIdx.y * 32;
    int tx = threadIdx.x, ty = threadIdx.y;
    #pragma unroll
    for (int j = 0; j < 32; j += 8)
        tile[ty + j][tx] = s[(size_t)(r0 + ty + j) * C + c0 + tx];
    __syncthreads();
    #pragma unroll
    for (int j = 0; j < 32; j += 8)
        d[(size_t)(c0 + ty + j) * R + r0 + tx] = tile[tx][ty + j];
}

// ---------------------------------------------------------------------------
// v0[b][c][m][h]: band-limited shifted FFT of z0 along x.
// ---------------------------------------------------------------------------
__global__ __launch_bounds__(256) void k_v0(const float* __restrict__ z0,
                                            const float* __restrict__ C,
                                            const float* __restrict__ S,
                                            float* __restrict__ v) {
    int m = blockIdx.x, b = blockIdx.y;
    int h = threadIdx.x & 127;
    int c = threadIdx.x >> 7;
    const float* zr = z0 + ((size_t)b * HID + h) * NX;
    const float* T  = (c == 0) ? (C + m * NX) : (S + m * NX);
    float acc = 0.f;
    for (int x = 0; x < NX; ++x) acc += zr[x] * T[x];
    if (c) acc = -acc;
    v[(((size_t)b * 2 + c) * MODES + m) * HID + h] = acc;
}

// ---------------------------------------------------------------------------
// K1 (per step): grid (NXT, BATCH), block 256.
//  Phase A: z[h, x-tile] from band-IDFT of v  -> LDS zs + zout
//  Phase B: H[b][x][o] = tanh(WFt z) + sum_n tanh(WGt z) * dxi
//  WFt[h][o], WGt[n][h][o] pre-transposed (lane-coalesced over o).
// ---------------------------------------------------------------------------
__global__ __launch_bounds__(256) void k_step1(
    const float* __restrict__ v, const float* __restrict__ Ct,
    const float* __restrict__ St, const float* __restrict__ WFt,
    const float* __restrict__ WGt, const float* __restrict__ dxi,
    float* __restrict__ H, float* __restrict__ zout, int step, int writeH,
    int zdirect)
{
    __shared__ float zs[XT][HID];
    __shared__ float Cs[MODES][XT];
    __shared__ float Ss[MODES][XT];
    __shared__ float dxs[XT][NF];
    int xt = blockIdx.x, b = blockIdx.y;
    int tid = threadIdx.x;
    int xg0 = xt * XT;

    for (int i = tid; i < MODES * XT; i += 256) {
        int m = i >> 2, xl = i & 3;
        Cs[m][xl] = Ct[m * NX + xg0 + xl];
        Ss[m][xl] = St[m * NX + xg0 + xl];
    }
    if (writeH && tid < XT * NF) {
        int xl = tid >> 2, n = tid & 3;
        dxs[xl][n] = dxi[(((size_t)step * BATCH + b) * NX + xg0 + xl) * NF + n];
    }
    __syncthreads();

    // ---- Phase A ----
    {
        int h  = tid & 127;
        int xp = tid >> 7;               // 0/1 -> xl = xp*2 + {0,1}
        const float* vr = v + ((size_t)b * 2 + 0) * MODES * HID + h;
        const float* vi = v + ((size_t)b * 2 + 1) * MODES * HID + h;
        float a0 = 0.f, a1 = 0.f;
        #pragma unroll 4
        for (int m = 0; m < MODES; ++m) {
            float r  = vr[m * HID];
            float im = vi[m * HID];
            a0 += r * Cs[m][xp * 2 + 0] - im * Ss[m][xp * 2 + 0];
            a1 += r * Cs[m][xp * 2 + 1] - im * Ss[m][xp * 2 + 1];
        }
        const float inv = 1.0f / (float)NX;
        a0 *= inv; a1 *= inv;
        zs[xp * 2 + 0][h] = a0;
        zs[xp * 2 + 1][h] = a1;
        if (zdirect) {
            size_t ob = (((size_t)b * HID + h) * NX + xg0 + xp * 2) * NT + step;
            zout[ob] = a0; zout[ob + NT] = a1;
        } else {
            size_t zb = (((size_t)(step & 15) * BATCH + b) * NX + xg0 + xp * 2) * HID + h;
            zout[zb] = a0; zout[zb + HID] = a1;
        }
    }
    __syncthreads();
    if (!writeH) return;

    // ---- Phase B ----
    {
        int o  = tid & 127;
        int xp = tid >> 7;
        int xl0 = xp * 2;
        float accF0 = 0.f, accF1 = 0.f;
        float accG[NF][2];
        #pragma unroll
        for (int n = 0; n < NF; ++n) { accG[n][0] = 0.f; accG[n][1] = 0.f; }
        const float* wf = WFt + o;
        const float* wg = WGt + o;
        #pragma unroll 2
        for (int h = 0; h < HID; ++h) {
            float z0v = zs[xl0][h];
            float z1v = zs[xl0 + 1][h];
            float f = wf[(size_t)h * HID];
            accF0 += f * z0v; accF1 += f * z1v;
            #pragma unroll
            for (int n = 0; n < NF; ++n) {
                float g = wg[((size_t)n * HID + h) * HID];
                accG[n][0] += g * z0v; accG[n][1] += g * z1v;
            }
        }
        float hv0 = tanhf(accF0), hv1 = tanhf(accF1);
        #pragma unroll
        for (int n = 0; n < NF; ++n) {
            hv0 += tanhf(accG[n][0]) * dxs[xl0][n];
            hv1 += tanhf(accG[n][1]) * dxs[xl0 + 1][n];
        }
        H[((size_t)b * NX + xg0 + xl0) * HID + o]     = hv0;
        H[((size_t)b * NX + xg0 + xl0 + 1) * HID + o] = hv1;
    }
}

// ---------------------------------------------------------------------------
// K2 (per step): grid (2, 96), block 256. At[c][m][h][o] pre-transposed.
//  H layout [b][x][o] -> FFT reads lane-coalesced over o.
// ---------------------------------------------------------------------------
__global__ __launch_bounds__(256) void k_step2(
    const float* __restrict__ vin, const float* __restrict__ At,
    const float* __restrict__ Ct, const float* __restrict__ St,
    const float* __restrict__ H, float* __restrict__ vout)
{
    int bp = blockIdx.x;   // 0/1 -> batch half
    int m  = blockIdx.y;
    int tid = threadIdx.x;
    __shared__ float vres[8][HID], vims[8][HID];
    __shared__ float Cs[NX], Ss[NX];
    if (tid < NX) { Cs[tid] = Ct[m * NX + tid]; Ss[tid] = St[m * NX + tid]; }
    for (int f = tid; f < 8 * HID; f += 256) {
        int bl = f >> 7, h = f & 127;
        int b = bp * 8 + bl;
        vres[bl][h] = vin[(((size_t)b * 2 + 0) * MODES + m) * HID + h];
        vims[bl][h] = vin[(((size_t)b * 2 + 1) * MODES + m) * HID + h];
    }
    __syncthreads();
    int o = tid & 127, bq = tid >> 7;   // each thread: 4 batches bl = bq*4+j
    float fre[4] = {0,0,0,0}, fim[4] = {0,0,0,0};
    #pragma unroll 2
    for (int x = 0; x < NX; ++x) {
        float c = Cs[x], s = Ss[x];
        #pragma unroll
        for (int j = 0; j < 4; ++j) {
            float hv = H[((size_t)(bp * 8 + bq * 4 + j) * NX + x) * HID + o];
            fre[j] += hv * c;
            fim[j] -= hv * s;
        }
    }
    const float* a0 = At + ((size_t)0 * MODES + m) * HID * HID + o;
    const float* a1 = At + ((size_t)1 * MODES + m) * HID * HID + o;
    float are[4] = {0,0,0,0}, aim[4] = {0,0,0,0};
    #pragma unroll 2
    for (int h = 0; h < HID; ++h) {
        float A0v = a0[(size_t)h * HID];
        float A1v = a1[(size_t)h * HID];
        #pragma unroll
        for (int j = 0; j < 4; ++j) {
            float r = vres[bq * 4 + j][h], i2 = vims[bq * 4 + j][h];
            are[j] += A0v * r - A1v * i2;
            aim[j] += A1v * r - A0v * i2;
        }
    }
    #pragma unroll
    for (int j = 0; j < 4; ++j) {
        int bl = bq * 4 + j, b = bp * 8 + bl;
        vout[(((size_t)b * 2 + 0) * MODES + m) * HID + o] = vres[bl][o] + are[j] + fre[j];
        vout[(((size_t)b * 2 + 1) * MODES + m) * HID + o] = vims[bl][o] + aim[j] + fim[j];
    }
}

// ---------------------------------------------------------------------------
// K2 fallback (no transposed A in ws): round-1 version.
// ---------------------------------------------------------------------------
__global__ __launch_bounds__(256) void k_step2_old(
    const float* __restrict__ vin, const float* __restrict__ A,
    const float* __restrict__ C, const float* __restrict__ S,
    const float* __restrict__ H, float* __restrict__ vout)
{
    int oq = blockIdx.x;
    int m  = blockIdx.y;
    int tid = threadIdx.x;
    __shared__ float vres[BATCH][HID];
    __shared__ float vims[BATCH][HID];
    __shared__ float Cs[NX], Ss[NX];
    if (tid < NX) { Cs[tid] = C[m * NX + tid]; Ss[tid] = S[m * NX + tid]; }
    for (int f = tid; f < BATCH * HID; f += 256) {
        int b = f >> 7, h = f & 127;
        vres[b][h] = vin[(((size_t)b * 2 + 0) * MODES + m) * HID + h];
        vims[b][h] = vin[(((size_t)b * 2 + 1) * MODES + m) * HID + h];
    }
    __syncthreads();
    const float* A0 = A + ((size_t)0 * MODES + m) * HID * HID;
    const float* A1 = A + ((size_t)1 * MODES + m) * HID * HID;
    #pragma unroll
    for (int pass = 0; pass < 2; ++pass) {
        int ol = tid & 31;
        int b  = (tid >> 5) + pass * 8;
        int o  = oq * 32 + ol;
        // H layout here is [b][x][o]
        float frev = 0.f, fimv = 0.f;
        for (int x = 0; x < NX; ++x) {
            float hv = H[((size_t)b * NX + x) * HID + o];
            frev += hv * Cs[x];
            fimv -= hv * Ss[x];
        }
        const float* a0 = A0 + (size_t)o * HID;
        const float* a1 = A1 + (size_t)o * HID;
        float are = 0.f, aim = 0.f;
        for (int h = 0; h < HID; ++h) {
            float r = vres[b][h], i2 = vims[b][h];
            are += a0[h] * r - a1[h] * i2;
            aim += a1[h] * r - a0[h] * i2;
        }
        vout[(((size_t)b * 2 + 0) * MODES + m) * HID + o] = vres[b][o] + are + frev;
        vout[(((size_t)b * 2 + 1) * MODES + m) * HID + o] = vims[b][o] + aim + fimv;
    }
}

// ---------------------------------------------------------------------------
// Flush: zbuf[tt][b][x][h] (16 steps) -> out[b][h][x][t0+tt] as 64B runs.
// grid (NX, BATCH), block 256.
// ---------------------------------------------------------------------------
__global__ __launch_bounds__(256) void k_flush(const float* __restrict__ zbuf,
                                               float* __restrict__ out, int t0) {
    int x = blockIdx.x, b = blockIdx.y, tid = threadIdx.x;
    __shared__ float tile[16][HID];
    for (int i = tid; i < 16 * HID; i += 256) {
        int tt = i >> 7, h = i & 127;
        tile[tt][h] = zbuf[(((size_t)tt * BATCH + b) * NX + x) * HID + h];
    }
    __syncthreads();
    int h = tid >> 1, half = tid & 1;
    float4 w[2];
    float* wp = (float*)w;
    #pragma unroll
    for (int j = 0; j < 8; ++j) wp[j] = tile[half * 8 + j][h];
    float4* dst = (float4*)(out + (((size_t)b * HID + h) * NX + x) * NT + t0 + half * 8);
    dst[0] = w[0];
    dst[1] = w[1];
}

// ---------------------------------------------------------------------------
extern "C" void kernel_launch(void* const* d_in, const int* in_sizes, int n_in,
                              void* d_out, int out_size, void* d_ws, size_t ws_size,
                              hipStream_t stream) {
    const float* z0 = (const float*)d_in[0];
    const float* xi = (const float*)d_in[1];
    const float* A  = (const float*)d_in[2];
    const float* WF = (const float*)d_in[3];
    const float* WG = (const float*)d_in[4];
    float* out = (float*)d_out;

    float* ws = (float*)d_ws;
    size_t cap = ws_size / sizeof(float);
    size_t off = 0;
    auto alloc = [&](size_t n) { float* p = ws + off; off += n; return p; };

    float* Ct   = alloc((size_t)MODES * NX);
    float* St   = alloc((size_t)MODES * NX);
    float* WFt  = alloc((size_t)HID * HID);
    float* WGt  = alloc((size_t)NF * HID * HID);
    float* v0b  = alloc((size_t)BATCH * 2 * MODES * HID);
    float* v1b  = alloc((size_t)BATCH * 2 * MODES * HID);
    float* Hb   = alloc((size_t)BATCH * NX * HID);
    float* dxib = alloc((size_t)(NT - 1) * BATCH * NX * NF);

    const size_t needAt = (size_t)2 * MODES * HID * HID;
    float* At = nullptr;
    if (off + needAt <= cap) At = alloc(needAt);
    const size_t needZ = (size_t)16 * BATCH * NX * HID;
    float* zbuf = nullptr;
    if (off + needZ <= cap) zbuf = alloc(needZ);

    k_tables<<<MODES, 128, 0, stream>>>(Ct, St);
    {
        int total = (NT - 1) * BATCH * NX * NF;
        k_dxi<<<(total + 255) / 256, 256, 0, stream>>>(xi, dxib);
    }
    k_transpose<<<dim3(4, 4, 1), dim3(32, 8), 0, stream>>>(WF, WFt, HID, HID);
    k_transpose<<<dim3(16, 4, 1), dim3(32, 8), 0, stream>>>(WG, WGt, HID, NF * HID);
    if (At)
        k_transpose<<<dim3(4, 4, 2 * MODES), dim3(32, 8), 0, stream>>>(A, At, HID, HID);
    k_v0<<<dim3(MODES, BATCH), 256, 0, stream>>>(z0, Ct, St, v0b);

    int zdirect = (zbuf == nullptr) ? 1 : 0;
    float* zout = zdirect ? out : zbuf;

    float* vcur = v0b;
    float* vnxt = v1b;
    for (int i = 0; i < NT - 1; ++i) {
        k_step1<<<dim3(NXT, BATCH), 256, 0, stream>>>(vcur, Ct, St, WFt, WGt,
                                                      dxib, Hb, zout, i, 1, zdirect);
        if (At)
            k_step2<<<dim3(2, MODES), 256, 0, stream>>>(vcur, At, Ct, St, Hb, vnxt);
        else
            k_step2_old<<<dim3(4, MODES), 256, 0, stream>>>(vcur, A, Ct, St, Hb, vnxt);
        float* t = vcur; vcur = vnxt; vnxt = t;
        if (!zdirect && (i & 15) == 15)
            k_flush<<<dim3(NX, BATCH), 256, 0, stream>>>(zbuf, out, i - 15);
    }
    k_step1<<<dim3(NXT, BATCH), 256, 0, stream>>>(vcur, Ct, St, WFt, WGt,
                                                  dxib, Hb, zout, NT - 1, 0, zdirect);
    if (!zdirect)
        k_flush<<<dim3(NX, BATCH), 256, 0, stream>>>(zbuf, out, NT - 16);
}

// Round 3
// 3701.981 us; speedup vs baseline: 1.7514x; 1.4101x over previous
//
#include <hip/hip_runtime.h>
#include <math.h>

#define BATCH 16
#define HID   128
#define NX    128
#define NF    4
#define NT    64
#define MODES 96
#define OM    (5 * HID)                      // 640 fused output rows (F + 4*G)
#define MATS  ((size_t)BATCH * HID * NX)     // Hp per-matrix stride

// ---------------------------------------------------------------------------
// Tables: C[m][x] = cos(2*pi*k_m*x/128), S[m][x] = sin, k_m=(80+m)%128.
// Also packed T2[m][x] = {c, s}.
// ---------------------------------------------------------------------------
__global__ void k_tables(float* __restrict__ C, float* __restrict__ S,
                         float2* __restrict__ T2) {
    int m = blockIdx.x;
    int x = threadIdx.x;
    if (x < NX) {
        int k = (80 + m) % NX;
        float ang = (float)((k * x) & (NX - 1)) * (2.0f * (float)M_PI / (float)NX);
        float c = cosf(ang), s = sinf(ang);
        C[m * NX + x] = c;
        S[m * NX + x] = s;
        T2[m * NX + x] = make_float2(c, s);
    }
}

// ---------------------------------------------------------------------------
// dxi[t][b][x][n] = xi[b,n,x,t+1] - xi[b,n,x,t]
// ---------------------------------------------------------------------------
__global__ void k_dxi(const float* __restrict__ xi, float* __restrict__ dxi) {
    int idx = blockIdx.x * blockDim.x + threadIdx.x;
    const int total = (NT - 1) * BATCH * NX * NF;
    if (idx < total) {
        int n = idx & (NF - 1);
        int x = (idx >> 2) & (NX - 1);
        int b = (idx >> 9) & (BATCH - 1);
        int t = idx >> 13;
        const float* base = xi + (((size_t)b * NF + n) * NX + x) * NT;
        dxi[idx] = base[t + 1] - base[t];
    }
}

// ---------------------------------------------------------------------------
// Wt[h][om] with om = g*128 + o; g=0 -> WF[o][h]; g=1..4 -> WG[o][g-1][h]
// grid (4,4,5), block (32,8)
// ---------------------------------------------------------------------------
__global__ void k_wt(const float* __restrict__ WF, const float* __restrict__ WG,
                     float* __restrict__ Wt) {
    __shared__ float t[32][33];
    int g = blockIdx.z;
    int h0 = blockIdx.x * 32, o0 = blockIdx.y * 32;
    int tx = threadIdx.x, ty = threadIdx.y;
    #pragma unroll
    for (int j = 0; j < 32; j += 8) {
        int o = o0 + ty + j;
        t[ty + j][tx] = (g == 0) ? WF[(size_t)o * HID + h0 + tx]
                                 : WG[((size_t)o * NF + (g - 1)) * HID + h0 + tx];
    }
    __syncthreads();
    #pragma unroll
    for (int j = 0; j < 32; j += 8)
        Wt[(size_t)(h0 + ty + j) * OM + g * HID + o0 + tx] = t[tx][ty + j];
}

// ---------------------------------------------------------------------------
// At2[m][h][o] = {A[0][m][o][h], A[1][m][o][h]}   grid (4,4,96), block (32,8)
// ---------------------------------------------------------------------------
__global__ void k_at2(const float* __restrict__ A, float2* __restrict__ At2) {
    __shared__ float t0[32][33], t1[32][33];
    int m = blockIdx.z;
    int h0 = blockIdx.x * 32, o0 = blockIdx.y * 32;
    int tx = threadIdx.x, ty = threadIdx.y;
    const float* A0 = A + (size_t)m * HID * HID;
    const float* A1 = A0 + (size_t)MODES * HID * HID;
    #pragma unroll
    for (int j = 0; j < 32; j += 8) {
        t0[ty + j][tx] = A0[(size_t)(o0 + ty + j) * HID + h0 + tx];
        t1[ty + j][tx] = A1[(size_t)(o0 + ty + j) * HID + h0 + tx];
    }
    __syncthreads();
    #pragma unroll
    for (int j = 0; j < 32; j += 8)
        At2[((size_t)m * HID + h0 + ty + j) * HID + o0 + tx] =
            make_float2(t0[tx][ty + j], t1[tx][ty + j]);
}

// ---------------------------------------------------------------------------
// v0[b][c][m][h]: band-limited shifted FFT of z0 (one-time).
// ---------------------------------------------------------------------------
__global__ __launch_bounds__(256) void k_v0(const float* __restrict__ z0,
                                            const float* __restrict__ C,
                                            const float* __restrict__ S,
                                            float* __restrict__ v) {
    int m = blockIdx.x, b = blockIdx.y;
    int h = threadIdx.x & 127;
    int c = threadIdx.x >> 7;
    const float* zr = z0 + ((size_t)b * HID + h) * NX;
    const float* T  = (c == 0) ? (C + m * NX) : (S + m * NX);
    float acc = 0.f;
    for (int x = 0; x < NX; ++x) acc += zr[x] * T[x];
    if (c) acc = -acc;
    v[(((size_t)b * 2 + c) * MODES + m) * HID + h] = acc;
}

// ---------------------------------------------------------------------------
// K1a: z[b][x][h] = (1/128) sum_m (vre*C - vim*S).  grid (16,16), block 512.
// Each thread: 2 x's. Writes zstep (and out directly if zdirect).
// ---------------------------------------------------------------------------
__global__ __launch_bounds__(512) void k_step1a(
    const float* __restrict__ v, const float* __restrict__ Ct,
    const float* __restrict__ St, float* __restrict__ zstep,
    float* __restrict__ out, int step, int zdirect)
{
    __shared__ float Cs[MODES][8], Ss[MODES][8];
    int xt = blockIdx.x, b = blockIdx.y;
    int tid = threadIdx.x;
    int xg0 = xt * 8;
    for (int i = tid; i < MODES * 8; i += 512) {
        int m = i >> 3, xl = i & 7;
        Cs[m][xl] = Ct[m * NX + xg0 + xl];
        Ss[m][xl] = St[m * NX + xg0 + xl];
    }
    __syncthreads();
    int h = tid & 127, xp = tid >> 7;
    int xl0 = xp * 2;
    const float* vr = v + ((size_t)b * 2) * MODES * HID + h;
    const float* vi = vr + (size_t)MODES * HID;
    float a0 = 0.f, a1 = 0.f;
    #pragma unroll 8
    for (int m = 0; m < MODES; ++m) {
        float r  = vr[m * HID];
        float im = vi[m * HID];
        a0 += r * Cs[m][xl0]     - im * Ss[m][xl0];
        a1 += r * Cs[m][xl0 + 1] - im * Ss[m][xl0 + 1];
    }
    const float inv = 1.0f / (float)NX;
    a0 *= inv; a1 *= inv;
    size_t zb = (((size_t)b * NX + xg0 + xl0) * HID) + h;
    zstep[zb] = a0;
    zstep[zb + HID] = a1;
    if (zdirect) {
        size_t ob = (((size_t)b * HID + h) * NX + xg0 + xl0) * NT + step;
        out[ob] = a0; out[ob + NT] = a1;
    }
}

// ---------------------------------------------------------------------------
// K1b: Hp[mat][b][o][x] = sum_h W[om][h] z[b][x][h]  (no tanh yet)
// GEMM: M=640 om, N=2048 bx, K=128. grid (64 bx-tiles, 10 om-tiles), block 256.
// Thread (bxt 16, ot 16): 4 om (one float4 of Wt) x 2 bx.
// ---------------------------------------------------------------------------
__global__ __launch_bounds__(256) void k_step1b(
    const float* __restrict__ zsrc, const float* __restrict__ Wt,
    float* __restrict__ Hp)
{
    __shared__ float zs[32][132];
    int bx0 = blockIdx.x * 32;
    int om0 = blockIdx.y * 64;
    int tid = threadIdx.x;
    // stage z-tile: 32 rows x 128 cols
    const float4* z4 = (const float4*)zsrc;
    #pragma unroll
    for (int p = 0; p < 4; ++p) {
        int idx = tid + p * 256;
        int row = idx >> 5, c4 = idx & 31;
        float4 zv = z4[(size_t)(bx0 + row) * 32 + c4];
        *((float4*)&zs[row][c4 * 4]) = zv;
    }
    __syncthreads();
    int bxt = tid & 15, ot = tid >> 4;
    const float4* W4 = (const float4*)Wt;      // [h][160]
    int wcol = (om0 >> 2) + ot;
    float a00=0,a01=0,a10=0,a11=0,a20=0,a21=0,a30=0,a31=0;
    #pragma unroll 4
    for (int h = 0; h < HID; ++h) {
        float4 w = W4[(size_t)h * (OM / 4) + wcol];
        float z0v = zs[bxt][h];
        float z1v = zs[bxt + 16][h];
        a00 += w.x * z0v; a01 += w.x * z1v;
        a10 += w.y * z0v; a11 += w.y * z1v;
        a20 += w.z * z0v; a21 += w.z * z1v;
        a30 += w.w * z0v; a31 += w.w * z1v;
    }
    int b = bx0 >> 7, x0 = bx0 & 127;
    float r0[4] = {a00, a10, a20, a30};
    float r1[4] = {a01, a11, a21, a31};
    #pragma unroll
    for (int j = 0; j < 4; ++j) {
        int om = om0 + ot * 4 + j;
        int mat = om >> 7, o = om & 127;
        size_t base = (((size_t)mat * BATCH + b) * HID + o) * NX + x0;
        Hp[base + bxt]      = r0[j];
        Hp[base + bxt + 16] = r1[j];
    }
}

// ---------------------------------------------------------------------------
// K2a: combine (tanh + dxi) then DFT over x.
// grid (16 b, 16 og of 8 o, 3 mg of 32 m), block 128.
// Phase1: Hc[o][x] = tanh(Hp0) + sum_n tanh(Hp_{n+1}) * dxi[n]
// Phase2: hf[c][m][b][o]; thread tile 4o x 2m, x-split 4 with LDS reduce.
// ---------------------------------------------------------------------------
__global__ __launch_bounds__(128) void k_step2a(
    const float* __restrict__ Hp, const float2* __restrict__ T2g,
    const float* __restrict__ dxi, float* __restrict__ hf, int step)
{
    __shared__ float Hcl[8][132];
    __shared__ float Csh[32][140];
    __shared__ float Ssh[32][140];
    __shared__ float red[4][32][16];
    int b = blockIdx.x, og = blockIdx.y, mg = blockIdx.z;
    int tid = threadIdx.x;

    // stage tables (32 m x 128 x)
    for (int p = 0; p < 32; ++p) {
        int idx = tid + p * 128;
        int mm = idx >> 7, x = idx & 127;
        float2 t = T2g[(size_t)(mg * 32 + mm) * NX + x];
        Csh[mm][x] = t.x;
        Ssh[mm][x] = t.y;
    }
    // combine: thread = x lane
    {
        int x = tid;
        const float4* dx4p = (const float4*)(dxi + (((size_t)step * BATCH + b) * NX + x) * NF);
        float4 dx = dx4p[0];
        const float* hp = Hp + ((size_t)b * HID + og * 8) * NX + x;
        #pragma unroll
        for (int o = 0; o < 8; ++o) {
            const float* p = hp + (size_t)o * NX;
            float f  = tanhf(p[0]);
            float g0 = tanhf(p[MATS]);
            float g1 = tanhf(p[2 * MATS]);
            float g2 = tanhf(p[3 * MATS]);
            float g3 = tanhf(p[4 * MATS]);
            Hcl[o][x] = f + g0 * dx.x + g1 * dx.y + g2 * dx.z + g3 * dx.w;
        }
    }
    __syncthreads();

    // DFT: thread (othr 2, mthr 16, xh 4); tile 4o x 2m over 32 x.
    int othr = tid & 1, mthr = (tid >> 1) & 15, xh = tid >> 5;
    int x0 = xh * 32;
    float re[4][2] = {}, im[4][2] = {};
    for (int i = 0; i < 32; i += 4) {
        float4 hc0 = *(const float4*)&Hcl[othr * 4 + 0][x0 + i];
        float4 hc1 = *(const float4*)&Hcl[othr * 4 + 1][x0 + i];
        float4 hc2 = *(const float4*)&Hcl[othr * 4 + 2][x0 + i];
        float4 hc3 = *(const float4*)&Hcl[othr * 4 + 3][x0 + i];
        #pragma unroll
        for (int mI = 0; mI < 2; ++mI) {
            float4 c4 = *(const float4*)&Csh[mthr * 2 + mI][x0 + i];
            float4 s4 = *(const float4*)&Ssh[mthr * 2 + mI][x0 + i];
            re[0][mI] += hc0.x*c4.x + hc0.y*c4.y + hc0.z*c4.z + hc0.w*c4.w;
            im[0][mI] -= hc0.x*s4.x + hc0.y*s4.y + hc0.z*s4.z + hc0.w*s4.w;
            re[1][mI] += hc1.x*c4.x + hc1.y*c4.y + hc1.z*c4.z + hc1.w*c4.w;
            im[1][mI] -= hc1.x*s4.x + hc1.y*s4.y + hc1.z*s4.z + hc1.w*s4.w;
            re[2][mI] += hc2.x*c4.x + hc2.y*c4.y + hc2.z*c4.z + hc2.w*c4.w;
            im[2][mI] -= hc2.x*s4.x + hc2.y*s4.y + hc2.z*s4.z + hc2.w*s4.w;
            re[3][mI] += hc3.x*c4.x + hc3.y*c4.y + hc3.z*c4.z + hc3.w*c4.w;
            im[3][mI] -= hc3.x*s4.x + hc3.y*s4.y + hc3.z*s4.z + hc3.w*s4.w;
        }
    }
    int slot = othr + 2 * mthr;
    #pragma unroll
    for (int oI = 0; oI < 4; ++oI)
        #pragma unroll
        for (int mI = 0; mI < 2; ++mI) {
            red[xh][slot][(oI * 2 + mI) * 2 + 0] = re[oI][mI];
            red[xh][slot][(oI * 2 + mI) * 2 + 1] = im[oI][mI];
        }
    __syncthreads();
    #pragma unroll
    for (int q = 0; q < 4; ++q) {
        int u = tid + q * 128;             // 512 outputs
        int o_l = u & 7, m_l = (u >> 3) & 31, ri = u >> 8;
        int so = o_l >> 2, oI = o_l & 3, sm = m_l >> 1, mI = m_l & 1;
        int sl = so + 2 * sm;
        int vv = (oI * 2 + mI) * 2 + ri;
        float sum = red[0][sl][vv] + red[1][sl][vv] + red[2][sl][vv] + red[3][sl][vv];
        hf[(((size_t)ri * MODES + mg * 32 + m_l) * BATCH + b) * HID + og * 8 + o_l] = sum;
    }
}

// ---------------------------------------------------------------------------
// K2b: vout = vin + Av + hf.  grid (4 oq, 2 bp, 96 m), block 256 (o32 x b8).
// At2[m][h][o] = {A0, A1}; faithful signs:
//   re = A0*r - A1*i ; im = A1*r - A0*i
// ---------------------------------------------------------------------------
__global__ __launch_bounds__(256) void k_step2b(
    const float* __restrict__ vin, const float2* __restrict__ At2,
    const float* __restrict__ hf, float* __restrict__ vout)
{
    __shared__ float2 vs2[8][HID];
    int oq = blockIdx.x, bp = blockIdx.y, m = blockIdx.z;
    int tid = threadIdx.x;
    for (int idx = tid; idx < 8 * HID; idx += 256) {
        int bb = idx >> 7, h = idx & 127;
        size_t base = (((size_t)(bp * 8 + bb) * 2) * MODES + m) * HID + h;
        vs2[bb][h] = make_float2(vin[base], vin[base + (size_t)MODES * HID]);
    }
    __syncthreads();
    int o = oq * 32 + (tid & 31);
    int bl = tid >> 5;
    int b = bp * 8 + bl;
    const float2* a2 = At2 + (size_t)m * HID * HID + o;
    float are = 0.f, aim = 0.f;
    #pragma unroll 4
    for (int h = 0; h < HID; ++h) {
        float2 a = a2[(size_t)h * HID];
        float2 vv = vs2[bl][h];
        are += a.x * vv.x - a.y * vv.y;
        aim += a.y * vv.x - a.x * vv.y;
    }
    float fre = hf[((size_t)m * BATCH + b) * HID + o];
    float fim = hf[(((size_t)MODES + m) * BATCH + b) * HID + o];
    float2 vo = vs2[bl][o];
    size_t ob = (((size_t)b * 2) * MODES + m) * HID + o;
    vout[ob] = vo.x + are + fre;
    vout[ob + (size_t)MODES * HID] = vo.y + aim + fim;
}

// ---------------------------------------------------------------------------
// Flush: zbuf[tt][b][x][h] (16 steps) -> out[b][h][x][t0+tt]
// ---------------------------------------------------------------------------
__global__ __launch_bounds__(256) void k_flush(const float* __restrict__ zbuf,
                                               float* __restrict__ out, int t0) {
    int x = blockIdx.x, b = blockIdx.y, tid = threadIdx.x;
    __shared__ float tile[16][HID];
    for (int i = tid; i < 16 * HID; i += 256) {
        int tt = i >> 7, h = i & 127;
        tile[tt][h] = zbuf[(((size_t)tt * BATCH + b) * NX + x) * HID + h];
    }
    __syncthreads();
    int h = tid >> 1, half = tid & 1;
    float4 w[2];
    float* wp = (float*)w;
    #pragma unroll
    for (int j = 0; j < 8; ++j) wp[j] = tile[half * 8 + j][h];
    float4* dst = (float4*)(out + (((size_t)b * HID + h) * NX + x) * NT + t0 + half * 8);
    dst[0] = w[0];
    dst[1] = w[1];
}

// ---------------------------------------------------------------------------
extern "C" void kernel_launch(void* const* d_in, const int* in_sizes, int n_in,
                              void* d_out, int out_size, void* d_ws, size_t ws_size,
                              hipStream_t stream) {
    const float* z0 = (const float*)d_in[0];
    const float* xi = (const float*)d_in[1];
    const float* A  = (const float*)d_in[2];
    const float* WF = (const float*)d_in[3];
    const float* WG = (const float*)d_in[4];
    float* out = (float*)d_out;

    float* ws = (float*)d_ws;
    size_t cap = ws_size / sizeof(float);
    size_t off = 0;
    auto alloc = [&](size_t n) { float* p = ws + off; off += n; return p; };

    float*  Ct   = alloc((size_t)MODES * NX);
    float*  St   = alloc((size_t)MODES * NX);
    float2* T2g  = (float2*)alloc((size_t)MODES * NX * 2);
    float*  Wt   = alloc((size_t)HID * OM);
    float2* At2  = (float2*)alloc((size_t)MODES * HID * HID * 2);
    float*  v0b  = alloc((size_t)BATCH * 2 * MODES * HID);
    float*  v1b  = alloc((size_t)BATCH * 2 * MODES * HID);
    float*  Hp   = alloc((size_t)5 * BATCH * HID * NX);
    float*  hfb  = alloc((size_t)2 * MODES * BATCH * HID);
    float*  dxib = alloc((size_t)(NT - 1) * BATCH * NX * NF);

    const size_t ZSZ = (size_t)BATCH * NX * HID;
    float* zbuf = nullptr;
    if (off + 16 * ZSZ <= cap) zbuf = alloc(16 * ZSZ);
    float* zsingle = nullptr;
    if (!zbuf) zsingle = alloc(ZSZ);
    int zdirect = (zbuf == nullptr) ? 1 : 0;

    // setup
    k_tables<<<MODES, 128, 0, stream>>>(Ct, St, T2g);
    {
        int total = (NT - 1) * BATCH * NX * NF;
        k_dxi<<<(total + 255) / 256, 256, 0, stream>>>(xi, dxib);
    }
    k_wt<<<dim3(4, 4, 5), dim3(32, 8), 0, stream>>>(WF, WG, Wt);
    k_at2<<<dim3(4, 4, MODES), dim3(32, 8), 0, stream>>>(A, At2);
    k_v0<<<dim3(MODES, BATCH), 256, 0, stream>>>(z0, Ct, St, v0b);

    float* vcur = v0b;
    float* vnxt = v1b;
    for (int i = 0; i < NT - 1; ++i) {
        float* zstep = zdirect ? zsingle : (zbuf + (size_t)(i & 15) * ZSZ);
        k_step1a<<<dim3(16, BATCH), 512, 0, stream>>>(vcur, Ct, St, zstep, out, i, zdirect);
        k_step1b<<<dim3(64, 10), 256, 0, stream>>>(zstep, Wt, Hp);
        k_step2a<<<dim3(BATCH, 16, 3), 128, 0, stream>>>(Hp, T2g, dxib, hfb, i);
        k_step2b<<<dim3(4, 2, MODES), 256, 0, stream>>>(vcur, At2, hfb, vnxt);
        float* t = vcur; vcur = vnxt; vnxt = t;
        if (!zdirect && (i & 15) == 15)
            k_flush<<<dim3(NX, BATCH), 256, 0, stream>>>(zbuf, out, i - 15);
    }
    {
        float* zstep = zdirect ? zsingle : (zbuf + (size_t)((NT - 1) & 15) * ZSZ);
        k_step1a<<<dim3(16, BATCH), 512, 0, stream>>>(vcur, Ct, St, zstep, out, NT - 1, zdirect);
        if (!zdirect)
            k_flush<<<dim3(NX, BATCH), 256, 0, stream>>>(zbuf, out, NT - 16);
    }
}